// Round 3
// baseline (2615.340 us; speedup 1.0000x reference)
//
#include <hip/hip_runtime.h>
#include <math.h>

typedef __bf16 bf16;
typedef __bf16 bf16x8 __attribute__((ext_vector_type(8)));
typedef float f32x4 __attribute__((ext_vector_type(4)));

#define B_ 2
#define S_ 1024
#define D_ 512
#define H_ 8
#define L_ 6
#define DK_ 64
#define DFF_ 2048
#define V_ 32000
#define MAXSEQ_ 1024
#define M_ 2048           // B_*S_
#define QT 8

// ---------------- block reduce helper (256 threads, 4 waves) ----------------
__device__ inline float blockReduceSum(float v, float* red) {
  for (int off = 32; off; off >>= 1) v += __shfl_xor(v, off, 64);
  int wid = threadIdx.x >> 6;
  __syncthreads();                       // protect red from previous use
  if ((threadIdx.x & 63) == 0) red[wid] = v;
  __syncthreads();
  return red[0] + red[1] + red[2] + red[3];
}

// ---------------- embedding + positional encoding ----------------
__global__ __launch_bounds__(256) void embed_kernel(const int* __restrict__ inp,
                                                    const float* __restrict__ emb,
                                                    float* __restrict__ x) {
  int i = blockIdx.x * 256 + threadIdx.x;      // over B*S*D = 1048576
  int d = i & (D_ - 1);
  int s = (i >> 9) & (S_ - 1);
  int b = i >> 19;
  int tok = inp[b * S_ + s];
  int j2 = d & ~1;
  float div = expf(-(float)j2 * (9.210340371976184f / (float)D_)); // ln(1e4)/D
  float ang = (float)s * div;
  float pe = (d & 1) ? cosf(ang) : sinf(ang);
  x[i] = emb[(size_t)tok * D_ + d] * 22.627416997969522f + pe;     // sqrt(512)
}

// ---------------- layer norm (ddof=1, a*(x-mean)/(std+eps)+b), bf16 out ----------------
__global__ __launch_bounds__(256) void ln_kernel(const float* __restrict__ X,
                                                 const float* __restrict__ ga,
                                                 const float* __restrict__ gb,
                                                 bf16* __restrict__ out) {
  __shared__ float red[4];
  int row = blockIdx.x;
  const float* xr = X + (size_t)row * D_;
  int t = threadIdx.x;
  float x0 = xr[t], x1 = xr[t + 256];
  float mean = blockReduceSum(x0 + x1, red) * (1.0f / (float)D_);
  float d0 = x0 - mean, d1 = x1 - mean;
  float var = blockReduceSum(d0 * d0 + d1 * d1, red) * (1.0f / (float)(D_ - 1));
  float rs = 1.0f / (sqrtf(var) + 1e-6f);
  bf16* orow = out + (size_t)row * D_;
  orow[t]       = (bf16)(ga[t] * d0 * rs + gb[t]);
  orow[t + 256] = (bf16)(ga[t + 256] * d1 * rs + gb[t + 256]);
}

// ---------------- GEMM: Y[m,n] = sum_k A[m,k]*W[n,k] (+bias) ----------------
// A: bf16 row-major MxK.  W: f32 row-major NxK (converted to bf16 during staging).
// EPI: 0 = f32 out, 1 = relu -> bf16 out, 3 = f32 out + residual add
template <int EPI>
__global__ __launch_bounds__(256) void gemm_bt(const bf16* __restrict__ A,
                                               const float* __restrict__ W,
                                               const float* __restrict__ bias,
                                               void* __restrict__ Yv,
                                               const float* __restrict__ res,
                                               int M, int N, int K) {
  __shared__ bf16 As[64][40];
  __shared__ bf16 Ws[64][40];
  int t = threadIdx.x;
  int n0 = blockIdx.x * 64, m0 = blockIdx.y * 64;
  int lrow = t >> 2, lseg = (t & 3) * 8;
  const bf16*  ag = A + (size_t)(m0 + lrow) * K + lseg;
  const float* wg = W + (size_t)(n0 + lrow) * K + lseg;
  int lane = t & 63, w = t >> 6;
  int wm = (w >> 1) * 32, wn = (w & 1) * 32;
  int fr = lane & 15, fk = (lane >> 4) * 8;
  f32x4 acc[2][2] = {};
  for (int kt = 0; kt < K; kt += 32) {
    *(uint4*)&As[lrow][lseg] = *(const uint4*)(ag + kt);
    float4 wa = *(const float4*)(wg + kt);
    float4 wb = *(const float4*)(wg + kt + 4);
    bf16x8 wv;
    wv[0] = (bf16)wa.x; wv[1] = (bf16)wa.y; wv[2] = (bf16)wa.z; wv[3] = (bf16)wa.w;
    wv[4] = (bf16)wb.x; wv[5] = (bf16)wb.y; wv[6] = (bf16)wb.z; wv[7] = (bf16)wb.w;
    *(bf16x8*)&Ws[lrow][lseg] = wv;
    __syncthreads();
    bf16x8 a0 = *(const bf16x8*)&As[wm + fr][fk];
    bf16x8 a1 = *(const bf16x8*)&As[wm + 16 + fr][fk];
    bf16x8 b0 = *(const bf16x8*)&Ws[wn + fr][fk];
    bf16x8 b1 = *(const bf16x8*)&Ws[wn + 16 + fr][fk];
    acc[0][0] = __builtin_amdgcn_mfma_f32_16x16x32_bf16(a0, b0, acc[0][0], 0, 0, 0);
    acc[0][1] = __builtin_amdgcn_mfma_f32_16x16x32_bf16(a0, b1, acc[0][1], 0, 0, 0);
    acc[1][0] = __builtin_amdgcn_mfma_f32_16x16x32_bf16(a1, b0, acc[1][0], 0, 0, 0);
    acc[1][1] = __builtin_amdgcn_mfma_f32_16x16x32_bf16(a1, b1, acc[1][1], 0, 0, 0);
    __syncthreads();
  }
  int oc = lane & 15, orr = (lane >> 4) * 4;
  #pragma unroll
  for (int mi = 0; mi < 2; mi++)
    #pragma unroll
    for (int ni = 0; ni < 2; ni++)
      #pragma unroll
      for (int j = 0; j < 4; j++) {
        int row = m0 + wm + mi * 16 + orr + j;
        int col = n0 + wn + ni * 16 + oc;
        float val = acc[mi][ni][j] + bias[col];
        size_t idx = (size_t)row * N + col;
        if constexpr (EPI == 0)      ((float*)Yv)[idx] = val;
        else if constexpr (EPI == 1) ((bf16*)Yv)[idx] = (bf16)fmaxf(val, 0.0f);
        else                         ((float*)Yv)[idx] = val + res[idx];
      }
}

// ---------------- relative-position bias: rb[b,h,k] = scale * dot(q[b,h,k,:], rel[h,k,:]) ----------------
__global__ __launch_bounds__(256) void relbias_kernel(const float* __restrict__ Q,
                                                      const float* __restrict__ rel_l,
                                                      float* __restrict__ rb) {
  int i = blockIdx.x * 256 + threadIdx.x;   // over B*H*S = 16384
  int k = i & (S_ - 1);
  int h = (i >> 10) & (H_ - 1);
  int b = i >> 13;
  const float* qp = Q + ((size_t)(b * S_ + k)) * D_ + h * DK_;
  const float* rp = rel_l + ((size_t)h * (MAXSEQ_ + 1) + k) * DK_;
  float s = 0.f;
  #pragma unroll
  for (int j = 0; j < DK_; j++) s += qp[j] * rp[j];
  rb[i] = s * 0.125f;                        // 1/sqrt(64)
}

// ---------------- causal attention with per-key bias ----------------
__global__ __launch_bounds__(256) void attn_kernel(const float* __restrict__ Q,
                                                   const float* __restrict__ K,
                                                   const float* __restrict__ V,
                                                   const float* __restrict__ rb,
                                                   bf16* __restrict__ Aout) {
  __shared__ float q_s[QT][68];
  __shared__ float s_s[QT][S_];
  __shared__ float kv_s[64][68];
  __shared__ float denom[QT];
  int t = threadIdx.x;
  int qb = blockIdx.x * QT;
  int h = blockIdx.y, b = blockIdx.z;
  const float* Qb = Q + ((size_t)(b * S_)) * D_ + h * DK_;
  const float* Kb = K + ((size_t)(b * S_)) * D_ + h * DK_;
  const float* Vb = V + ((size_t)(b * S_)) * D_ + h * DK_;
  const float* rbb = rb + (b * H_ + h) * S_;

  for (int e = t; e < QT * 64; e += 256) {
    int r = e >> 6, j = e & 63;
    q_s[r][j] = Qb[(size_t)(qb + r) * D_ + j] * 0.125f;
  }
  int nkt = qb / 64 + 1;
  int klimit = nkt * 64;
  int lrow = t >> 2, lc = (t & 3) * 16;
  int kl = t & 63, rg = t >> 6;
  __syncthreads();

  // phase 1: scores
  for (int kt = 0; kt < nkt; kt++) {
    int kb = kt * 64;
    #pragma unroll
    for (int i = 0; i < 16; i += 4)
      *(float4*)&kv_s[lrow][lc + i] = *(const float4*)&Kb[(size_t)(kb + lrow) * D_ + lc + i];
    __syncthreads();
    float a0 = 0.f, a1 = 0.f;
    #pragma unroll
    for (int j = 0; j < 64; j += 4) {
      float4 kv = *(float4*)&kv_s[kl][j];
      float4 qa = *(float4*)&q_s[rg][j];
      float4 qc = *(float4*)&q_s[rg + 4][j];
      a0 += kv.x * qa.x + kv.y * qa.y + kv.z * qa.z + kv.w * qa.w;
      a1 += kv.x * qc.x + kv.y * qc.y + kv.z * qc.z + kv.w * qc.w;
    }
    int kg = kb + kl;
    float bb = rbb[kg];
    s_s[rg][kg]     = (kg <= qb + rg)     ? a0 + bb : -1e9f;
    s_s[rg + 4][kg] = (kg <= qb + rg + 4) ? a1 + bb : -1e9f;
    __syncthreads();
  }

  // phase 2: softmax (32 lanes per row)
  {
    int row = t >> 5, l32 = t & 31;
    float m = -1e30f;
    for (int k2 = l32; k2 < klimit; k2 += 32) m = fmaxf(m, s_s[row][k2]);
    for (int off = 16; off; off >>= 1) m = fmaxf(m, __shfl_xor(m, off, 32));
    float sum = 0.f;
    for (int k2 = l32; k2 < klimit; k2 += 32) {
      float p = __expf(s_s[row][k2] - m);
      s_s[row][k2] = p;
      sum += p;
    }
    for (int off = 16; off; off >>= 1) sum += __shfl_xor(sum, off, 32);
    if (l32 == 0) denom[row] = sum;
  }
  __syncthreads();

  // phase 3: PV
  float o0 = 0.f, o1 = 0.f;
  for (int kt = 0; kt < nkt; kt++) {
    int kb = kt * 64;
    #pragma unroll
    for (int i = 0; i < 16; i += 4)
      *(float4*)&kv_s[lrow][lc + i] = *(const float4*)&Vb[(size_t)(kb + lrow) * D_ + lc + i];
    __syncthreads();
    #pragma unroll 4
    for (int kk = 0; kk < 64; kk++) {
      float vv = kv_s[kk][kl];
      o0 += s_s[rg][kb + kk] * vv;
      o1 += s_s[rg + 4][kb + kk] * vv;
    }
    __syncthreads();
  }
  float i0 = 1.0f / denom[rg], i1 = 1.0f / denom[rg + 4];
  Aout[(size_t)(b * S_ + qb + rg) * D_ + h * DK_ + kl]     = (bf16)(o0 * i0);
  Aout[(size_t)(b * S_ + qb + rg + 4) * D_ + h * DK_ + kl] = (bf16)(o1 * i1);
}

// ---------------- in-place log-softmax over V_ per row ----------------
__global__ __launch_bounds__(256) void lsm_kernel(float* __restrict__ X) {
  __shared__ float redm[4], reds[4], sh[1];
  int row = blockIdx.x;
  float* xr = X + (size_t)row * V_;
  int t = threadIdx.x;
  float m = -1e30f, s = 0.f;
  for (int k = t; k < V_; k += 256) {
    float v = xr[k];
    if (v > m) { s *= __expf(m - v); m = v; }
    s += __expf(v - m);
  }
  for (int off = 32; off; off >>= 1) {
    float m2 = __shfl_xor(m, off, 64);
    float s2 = __shfl_xor(s, off, 64);
    float mn = fmaxf(m, m2);
    s = s * __expf(m - mn) + s2 * __expf(m2 - mn);
    m = mn;
  }
  int wid = t >> 6;
  if ((t & 63) == 0) { redm[wid] = m; reds[wid] = s; }
  __syncthreads();
  if (t == 0) {
    float M2 = redm[0], SS = reds[0];
    for (int i2 = 1; i2 < 4; i2++) {
      float mn = fmaxf(M2, redm[i2]);
      SS = SS * __expf(M2 - mn) + reds[i2] * __expf(redm[i2] - mn);
      M2 = mn;
    }
    sh[0] = M2 + logf(SS);
  }
  __syncthreads();
  float lz = sh[0];
  for (int k = t; k < V_; k += 256) xr[k] = xr[k] - lz;
}

// ---------------- launch ----------------
extern "C" void kernel_launch(void* const* d_in, const int* in_sizes, int n_in,
                              void* d_out, int out_size, void* d_ws, size_t ws_size,
                              hipStream_t stream) {
  const int*   inp  = (const int*)d_in[0];
  const float* emb  = (const float*)d_in[2];
  const float* Wq   = (const float*)d_in[3];
  const float* bq   = (const float*)d_in[4];
  const float* Wk   = (const float*)d_in[5];
  const float* bk   = (const float*)d_in[6];
  const float* Wv   = (const float*)d_in[7];
  const float* bv   = (const float*)d_in[8];
  const float* Wo   = (const float*)d_in[9];
  const float* bo   = (const float*)d_in[10];
  const float* rel  = (const float*)d_in[11];
  const float* ln1a = (const float*)d_in[12];
  const float* ln1b = (const float*)d_in[13];
  const float* ln2a = (const float*)d_in[14];
  const float* ln2b = (const float*)d_in[15];
  const float* W1   = (const float*)d_in[16];
  const float* b1   = (const float*)d_in[17];
  const float* W2   = (const float*)d_in[18];
  const float* b2   = (const float*)d_in[19];
  const float* lnfa = (const float*)d_in[20];
  const float* lnfb = (const float*)d_in[21];
  const float* Wg   = (const float*)d_in[22];
  const float* bg   = (const float*)d_in[23];

  char* wp = (char*)d_ws;
  auto alloc = [&](size_t bytes) { void* p = wp; wp += (bytes + 255) & ~255ULL; return p; };
  float* x     = (float*)alloc((size_t)M_ * D_ * 4);
  bf16*  hbuf  = (bf16*) alloc((size_t)M_ * D_ * 2);
  float* q     = (float*)alloc((size_t)M_ * D_ * 4);
  float* kbuf  = (float*)alloc((size_t)M_ * D_ * 4);
  float* v     = (float*)alloc((size_t)M_ * D_ * 4);
  bf16*  abuf  = (bf16*) alloc((size_t)M_ * D_ * 2);
  bf16*  ffn   = (bf16*) alloc((size_t)M_ * DFF_ * 2);
  float* rbias = (float*)alloc((size_t)B_ * H_ * S_ * 4);

  embed_kernel<<<dim3((M_ * D_) / 256), 256, 0, stream>>>(inp, emb, x);

  dim3 g512(D_ / 64, M_ / 64);
  dim3 gff(DFF_ / 64, M_ / 64);
  for (int l = 0; l < L_; l++) {
    ln_kernel<<<M_, 256, 0, stream>>>(x, ln1a + l * D_, ln1b + l * D_, hbuf);
    gemm_bt<0><<<g512, 256, 0, stream>>>(hbuf, Wq + (size_t)l * D_ * D_, bq + l * D_, q,    nullptr, M_, D_, D_);
    gemm_bt<0><<<g512, 256, 0, stream>>>(hbuf, Wk + (size_t)l * D_ * D_, bk + l * D_, kbuf, nullptr, M_, D_, D_);
    gemm_bt<0><<<g512, 256, 0, stream>>>(hbuf, Wv + (size_t)l * D_ * D_, bv + l * D_, v,    nullptr, M_, D_, D_);
    relbias_kernel<<<dim3((B_ * H_ * S_) / 256), 256, 0, stream>>>(q, rel + (size_t)l * H_ * (MAXSEQ_ + 1) * DK_, rbias);
    attn_kernel<<<dim3(S_ / QT, H_, B_), 256, 0, stream>>>(q, kbuf, v, rbias, abuf);
    gemm_bt<3><<<g512, 256, 0, stream>>>(abuf, Wo + (size_t)l * D_ * D_, bo + l * D_, x, x, M_, D_, D_);
    ln_kernel<<<M_, 256, 0, stream>>>(x, ln2a + l * D_, ln2b + l * D_, hbuf);
    gemm_bt<1><<<gff, 256, 0, stream>>>(hbuf, W1 + (size_t)l * DFF_ * D_, b1 + l * DFF_, ffn, nullptr, M_, DFF_, D_);
    gemm_bt<3><<<g512, 256, 0, stream>>>(ffn, W2 + (size_t)l * D_ * DFF_, b2 + l * D_, x, x, M_, D_, DFF_);
  }
  ln_kernel<<<M_, 256, 0, stream>>>(x, lnfa, lnfb, hbuf);
  dim3 gv(V_ / 64, M_ / 64);
  gemm_bt<0><<<gv, 256, 0, stream>>>(hbuf, Wg, bg, (float*)d_out, nullptr, M_, V_, D_);
  lsm_kernel<<<M_, 256, 0, stream>>>((float*)d_out);
}

// Round 4
// 2221.262 us; speedup vs baseline: 1.1774x; 1.1774x over previous
//
#include <hip/hip_runtime.h>
#include <math.h>

typedef __bf16 bf16;
typedef __bf16 bf16x8 __attribute__((ext_vector_type(8)));
typedef float f32x4 __attribute__((ext_vector_type(4)));

#define B_ 2
#define S_ 1024
#define D_ 512
#define H_ 8
#define L_ 6
#define DK_ 64
#define DFF_ 2048
#define V_ 32000
#define MAXSEQ_ 1024
#define M_ 2048           // B_*S_
#define QT 8
#define QKV_ 1536         // 3*D_

#define GLDS16(g, l) __builtin_amdgcn_global_load_lds((const __attribute__((address_space(1))) void*)(g), (__attribute__((address_space(3))) void*)(l), 16, 0, 0)

// ---------------- block reduce helper (256 threads, 4 waves) ----------------
__device__ inline float blockReduceSum(float v, float* red) {
  for (int off = 32; off; off >>= 1) v += __shfl_xor(v, off, 64);
  int wid = threadIdx.x >> 6;
  __syncthreads();
  if ((threadIdx.x & 63) == 0) red[wid] = v;
  __syncthreads();
  return red[0] + red[1] + red[2] + red[3];
}

// ---------------- weight conversion: f32 -> bf16 ----------------
__global__ __launch_bounds__(256) void convw_kernel(const float* __restrict__ src,
                                                    bf16* __restrict__ dst, int n) {
  int i = (blockIdx.x * 256 + threadIdx.x) * 4;
  if (i < n) {
    float4 v = *(const float4*)(src + i);
    dst[i]     = (bf16)v.x;
    dst[i + 1] = (bf16)v.y;
    dst[i + 2] = (bf16)v.z;
    dst[i + 3] = (bf16)v.w;
  }
}

// merged QKV weights: dst[l][r][c], r in [0,1536): 0-511 Wq rows, 512-1023 Wk, 1024-1535 Wv
__global__ __launch_bounds__(256) void convqkv_kernel(const float* __restrict__ Wq,
                                                      const float* __restrict__ Wk,
                                                      const float* __restrict__ Wv,
                                                      bf16* __restrict__ dst) {
  int i = (blockIdx.x * 256 + threadIdx.x) * 4;   // over L_*QKV_*D_ = 4718592
  int l = i / (QKV_ * D_);
  int rem = i - l * (QKV_ * D_);
  int r = rem >> 9;
  int c = i & (D_ - 1);
  int which = r >> 9, rr = r & 511;
  const float* src = (which == 0 ? Wq : which == 1 ? Wk : Wv) + ((size_t)l * D_ + rr) * D_ + c;
  float4 v = *(const float4*)src;
  dst[i]     = (bf16)v.x;
  dst[i + 1] = (bf16)v.y;
  dst[i + 2] = (bf16)v.z;
  dst[i + 3] = (bf16)v.w;
}

__global__ __launch_bounds__(256) void convbqkv_kernel(const float* __restrict__ bq,
                                                       const float* __restrict__ bk,
                                                       const float* __restrict__ bv,
                                                       float* __restrict__ dst) {
  int i = blockIdx.x * 256 + threadIdx.x;          // over L_*QKV_ = 9216
  if (i >= L_ * QKV_) return;
  int l = i / QKV_, r = i - l * QKV_;
  int which = r >> 9, rr = r & 511;
  const float* s = (which == 0 ? bq : which == 1 ? bk : bv);
  dst[i] = s[l * D_ + rr];
}

// ---------------- embedding + positional encoding ----------------
__global__ __launch_bounds__(256) void embed_kernel(const int* __restrict__ inp,
                                                    const float* __restrict__ emb,
                                                    float* __restrict__ x) {
  int i = blockIdx.x * 256 + threadIdx.x;
  int d = i & (D_ - 1);
  int s = (i >> 9) & (S_ - 1);
  int b = i >> 19;
  int tok = inp[b * S_ + s];
  int j2 = d & ~1;
  float div = expf(-(float)j2 * (9.210340371976184f / (float)D_));
  float ang = (float)s * div;
  float pe = (d & 1) ? cosf(ang) : sinf(ang);
  x[i] = emb[(size_t)tok * D_ + d] * 22.627416997969522f + pe;
}

// ---------------- layer norm ----------------
__global__ __launch_bounds__(256) void ln_kernel(const float* __restrict__ X,
                                                 const float* __restrict__ ga,
                                                 const float* __restrict__ gb,
                                                 bf16* __restrict__ out) {
  __shared__ float red[4];
  int row = blockIdx.x;
  const float* xr = X + (size_t)row * D_;
  int t = threadIdx.x;
  float x0 = xr[t], x1 = xr[t + 256];
  float mean = blockReduceSum(x0 + x1, red) * (1.0f / (float)D_);
  float d0 = x0 - mean, d1 = x1 - mean;
  float var = blockReduceSum(d0 * d0 + d1 * d1, red) * (1.0f / (float)(D_ - 1));
  float rs = 1.0f / (sqrtf(var) + 1e-6f);
  bf16* orow = out + (size_t)row * D_;
  orow[t]       = (bf16)(ga[t] * d0 * rs + gb[t]);
  orow[t + 256] = (bf16)(ga[t + 256] * d1 * rs + gb[t + 256]);
}

// ---------------- GEMM 128x128 tile (m97 structure): Y[m,n] = sum_k A[m,k]*W[n,k] + bias ----------------
// A bf16 MxK row-major, W bf16 NxK row-major. BK=32, 4 waves (2x2), 4x4 16x16x32 frags/wave.
// EPI: 0 = f32 out, 1 = relu -> bf16 out, 3 = f32 out + residual add
template <int EPI>
__global__ __launch_bounds__(256) void gemm128(const bf16* __restrict__ A,
                                               const bf16* __restrict__ W,
                                               const float* __restrict__ bias,
                                               void* __restrict__ Yv,
                                               const float* __restrict__ res,
                                               int M, int N, int K) {
  __shared__ __align__(16) bf16 As[128 * 32];
  __shared__ __align__(16) bf16 Bs[128 * 32];
  int t = threadIdx.x;
  int lane = t & 63, w = t >> 6;
  int n0 = blockIdx.x * 128, m0 = blockIdx.y * 128;
  // staging: wave w handles 1KB chunks {w, w+4}; lane l: row 16c + l/4, col elems (l&3)*8
  int sr = lane >> 2, sc = (lane & 3) * 8;
  const bf16* ag0 = A + (size_t)(m0 + w * 16 + sr) * K + sc;
  const bf16* ag1 = A + (size_t)(m0 + (w + 4) * 16 + sr) * K + sc;
  const bf16* wg0 = W + (size_t)(n0 + w * 16 + sr) * K + sc;
  const bf16* wg1 = W + (size_t)(n0 + (w + 4) * 16 + sr) * K + sc;
  bf16* la0 = &As[w * 512];
  bf16* la1 = &As[(w + 4) * 512];
  bf16* lb0 = &Bs[w * 512];
  bf16* lb1 = &Bs[(w + 4) * 512];
  int wm = (w >> 1) * 64, wn = (w & 1) * 64;
  int fr = lane & 15, fk = (lane >> 4) * 8;
  f32x4 acc[4][4] = {};
  for (int kt = 0; kt < K; kt += 32) {
    GLDS16(ag0 + kt, la0);
    GLDS16(ag1 + kt, la1);
    GLDS16(wg0 + kt, lb0);
    GLDS16(wg1 + kt, lb1);
    __syncthreads();                       // compiler drains vmcnt before s_barrier
    bf16x8 af[4], bfr[4];
    #pragma unroll
    for (int i = 0; i < 4; i++) af[i]  = *(const bf16x8*)&As[(wm + i * 16 + fr) * 32 + fk];
    #pragma unroll
    for (int i = 0; i < 4; i++) bfr[i] = *(const bf16x8*)&Bs[(wn + i * 16 + fr) * 32 + fk];
    #pragma unroll
    for (int mi = 0; mi < 4; mi++)
      #pragma unroll
      for (int ni = 0; ni < 4; ni++)
        acc[mi][ni] = __builtin_amdgcn_mfma_f32_16x16x32_bf16(af[mi], bfr[ni], acc[mi][ni], 0, 0, 0);
    __syncthreads();
  }
  int oc = lane & 15, orr = (lane >> 4) * 4;
  #pragma unroll
  for (int mi = 0; mi < 4; mi++)
    #pragma unroll
    for (int ni = 0; ni < 4; ni++)
      #pragma unroll
      for (int j = 0; j < 4; j++) {
        int row = m0 + wm + mi * 16 + orr + j;
        int col = n0 + wn + ni * 16 + oc;
        float val = acc[mi][ni][j] + bias[col];
        size_t idx = (size_t)row * N + col;
        if constexpr (EPI == 0)      ((float*)Yv)[idx] = val;
        else if constexpr (EPI == 1) ((bf16*)Yv)[idx] = (bf16)fmaxf(val, 0.0f);
        else                         ((float*)Yv)[idx] = val + res[idx];
      }
}

// ---------------- relative-position bias ----------------
__global__ __launch_bounds__(256) void relbias_kernel(const float* __restrict__ Q,
                                                      const float* __restrict__ rel_l,
                                                      float* __restrict__ rb) {
  int i = blockIdx.x * 256 + threadIdx.x;   // over B*H*S = 16384
  int k = i & (S_ - 1);
  int h = (i >> 10) & (H_ - 1);
  int b = i >> 13;
  const float* qp = Q + ((size_t)(b * S_ + k)) * QKV_ + h * DK_;
  const float* rp = rel_l + ((size_t)h * (MAXSEQ_ + 1) + k) * DK_;
  float s = 0.f;
  #pragma unroll
  for (int j = 0; j < DK_; j++) s += qp[j] * rp[j];
  rb[i] = s * 0.125f;
}

// ---------------- causal attention with per-key bias (qkv packed, stride QKV_) ----------------
__global__ __launch_bounds__(256) void attn_kernel(const float* __restrict__ QKV,
                                                   const float* __restrict__ rb,
                                                   bf16* __restrict__ Aout) {
  __shared__ float q_s[QT][68];
  __shared__ float s_s[QT][S_];
  __shared__ float kv_s[64][68];
  __shared__ float denom[QT];
  int t = threadIdx.x;
  int qb = blockIdx.x * QT;
  int h = blockIdx.y, b = blockIdx.z;
  const float* Qb = QKV + (size_t)(b * S_) * QKV_ + h * DK_;
  const float* Kb = Qb + D_;
  const float* Vb = Qb + 2 * D_;
  const float* rbb = rb + (b * H_ + h) * S_;

  for (int e = t; e < QT * 64; e += 256) {
    int r = e >> 6, j = e & 63;
    q_s[r][j] = Qb[(size_t)(qb + r) * QKV_ + j] * 0.125f;
  }
  int nkt = qb / 64 + 1;
  int klimit = nkt * 64;
  int lrow = t >> 2, lc = (t & 3) * 16;
  int kl = t & 63, rg = t >> 6;
  __syncthreads();

  // phase 1: scores
  for (int kt = 0; kt < nkt; kt++) {
    int kb = kt * 64;
    #pragma unroll
    for (int i = 0; i < 16; i += 4)
      *(float4*)&kv_s[lrow][lc + i] = *(const float4*)&Kb[(size_t)(kb + lrow) * QKV_ + lc + i];
    __syncthreads();
    float a0 = 0.f, a1 = 0.f;
    #pragma unroll
    for (int j = 0; j < 64; j += 4) {
      float4 kv = *(float4*)&kv_s[kl][j];
      float4 qa = *(float4*)&q_s[rg][j];
      float4 qc = *(float4*)&q_s[rg + 4][j];
      a0 += kv.x * qa.x + kv.y * qa.y + kv.z * qa.z + kv.w * qa.w;
      a1 += kv.x * qc.x + kv.y * qc.y + kv.z * qc.z + kv.w * qc.w;
    }
    int kg = kb + kl;
    float bb = rbb[kg];
    s_s[rg][kg]     = (kg <= qb + rg)     ? a0 + bb : -1e9f;
    s_s[rg + 4][kg] = (kg <= qb + rg + 4) ? a1 + bb : -1e9f;
    __syncthreads();
  }

  // phase 2: softmax (32 lanes per row)
  {
    int row = t >> 5, l32 = t & 31;
    float m = -1e30f;
    for (int k2 = l32; k2 < klimit; k2 += 32) m = fmaxf(m, s_s[row][k2]);
    for (int off = 16; off; off >>= 1) m = fmaxf(m, __shfl_xor(m, off, 32));
    float sum = 0.f;
    for (int k2 = l32; k2 < klimit; k2 += 32) {
      float p = __expf(s_s[row][k2] - m);
      s_s[row][k2] = p;
      sum += p;
    }
    for (int off = 16; off; off >>= 1) sum += __shfl_xor(sum, off, 32);
    if (l32 == 0) denom[row] = sum;
  }
  __syncthreads();

  // phase 3: PV
  float o0 = 0.f, o1 = 0.f;
  for (int kt = 0; kt < nkt; kt++) {
    int kb = kt * 64;
    #pragma unroll
    for (int i = 0; i < 16; i += 4)
      *(float4*)&kv_s[lrow][lc + i] = *(const float4*)&Vb[(size_t)(kb + lrow) * QKV_ + lc + i];
    __syncthreads();
    #pragma unroll 4
    for (int kk = 0; kk < 64; kk++) {
      float vv = kv_s[kk][kl];
      o0 += s_s[rg][kb + kk] * vv;
      o1 += s_s[rg + 4][kb + kk] * vv;
    }
    __syncthreads();
  }
  float i0 = 1.0f / denom[rg], i1 = 1.0f / denom[rg + 4];
  Aout[(size_t)(b * S_ + qb + rg) * D_ + h * DK_ + kl]     = (bf16)(o0 * i0);
  Aout[(size_t)(b * S_ + qb + rg + 4) * D_ + h * DK_ + kl] = (bf16)(o1 * i1);
}

// ---------------- in-place log-softmax over V_ per row ----------------
__global__ __launch_bounds__(256) void lsm_kernel(float* __restrict__ X) {
  __shared__ float redm[4], reds[4], sh[1];
  int row = blockIdx.x;
  float* xr = X + (size_t)row * V_;
  int t = threadIdx.x;
  float m = -1e30f, s = 0.f;
  for (int k = t; k < V_; k += 256) {
    float v = xr[k];
    if (v > m) { s *= __expf(m - v); m = v; }
    s += __expf(v - m);
  }
  for (int off = 32; off; off >>= 1) {
    float m2 = __shfl_xor(m, off, 64);
    float s2 = __shfl_xor(s, off, 64);
    float mn = fmaxf(m, m2);
    s = s * __expf(m - mn) + s2 * __expf(m2 - mn);
    m = mn;
  }
  int wid = t >> 6;
  if ((t & 63) == 0) { redm[wid] = m; reds[wid] = s; }
  __syncthreads();
  if (t == 0) {
    float M2 = redm[0], SS = reds[0];
    for (int i2 = 1; i2 < 4; i2++) {
      float mn = fmaxf(M2, redm[i2]);
      SS = SS * __expf(M2 - mn) + reds[i2] * __expf(redm[i2] - mn);
      M2 = mn;
    }
    sh[0] = M2 + logf(SS);
  }
  __syncthreads();
  float lz = sh[0];
  for (int k = t; k < V_; k += 256) xr[k] = xr[k] - lz;
}

// ---------------- launch ----------------
extern "C" void kernel_launch(void* const* d_in, const int* in_sizes, int n_in,
                              void* d_out, int out_size, void* d_ws, size_t ws_size,
                              hipStream_t stream) {
  const int*   inp  = (const int*)d_in[0];
  const float* emb  = (const float*)d_in[2];
  const float* Wq   = (const float*)d_in[3];
  const float* bq   = (const float*)d_in[4];
  const float* Wk   = (const float*)d_in[5];
  const float* bk   = (const float*)d_in[6];
  const float* Wv   = (const float*)d_in[7];
  const float* bv   = (const float*)d_in[8];
  const float* Wo   = (const float*)d_in[9];
  const float* bo   = (const float*)d_in[10];
  const float* rel  = (const float*)d_in[11];
  const float* ln1a = (const float*)d_in[12];
  const float* ln1b = (const float*)d_in[13];
  const float* ln2a = (const float*)d_in[14];
  const float* ln2b = (const float*)d_in[15];
  const float* W1   = (const float*)d_in[16];
  const float* b1   = (const float*)d_in[17];
  const float* W2   = (const float*)d_in[18];
  const float* b2   = (const float*)d_in[19];
  const float* lnfa = (const float*)d_in[20];
  const float* lnfb = (const float*)d_in[21];
  const float* Wg   = (const float*)d_in[22];
  const float* bg   = (const float*)d_in[23];

  char* wp = (char*)d_ws;
  auto alloc = [&](size_t bytes) { void* p = wp; wp += (bytes + 255) & ~255ULL; return p; };
  float* x     = (float*)alloc((size_t)M_ * D_ * 4);
  bf16*  hbuf  = (bf16*) alloc((size_t)M_ * D_ * 2);
  float* qkv   = (float*)alloc((size_t)M_ * QKV_ * 4);
  bf16*  abuf  = (bf16*) alloc((size_t)M_ * D_ * 2);
  bf16*  ffn   = (bf16*) alloc((size_t)M_ * DFF_ * 2);
  float* rbias = (float*)alloc((size_t)B_ * H_ * S_ * 4);
  bf16*  wqkvB = (bf16*) alloc((size_t)L_ * QKV_ * D_ * 2);
  float* bqkvB = (float*)alloc((size_t)L_ * QKV_ * 4);
  bf16*  woB   = (bf16*) alloc((size_t)L_ * D_ * D_ * 2);
  bf16*  w1B   = (bf16*) alloc((size_t)L_ * DFF_ * D_ * 2);
  bf16*  w2B   = (bf16*) alloc((size_t)L_ * D_ * DFF_ * 2);
  bf16*  wgB   = (bf16*) alloc((size_t)V_ * D_ * 2);

  // weight conversions (per call; deterministic)
  convqkv_kernel<<<dim3(L_ * QKV_ * D_ / 1024), 256, 0, stream>>>(Wq, Wk, Wv, wqkvB);
  convbqkv_kernel<<<dim3((L_ * QKV_ + 255) / 256), 256, 0, stream>>>(bq, bk, bv, bqkvB);
  convw_kernel<<<dim3(L_ * D_ * D_ / 1024), 256, 0, stream>>>(Wo, woB, L_ * D_ * D_);
  convw_kernel<<<dim3(L_ * DFF_ * D_ / 1024), 256, 0, stream>>>(W1, w1B, L_ * DFF_ * D_);
  convw_kernel<<<dim3(L_ * D_ * DFF_ / 1024), 256, 0, stream>>>(W2, w2B, L_ * D_ * DFF_);
  convw_kernel<<<dim3(V_ * D_ / 1024), 256, 0, stream>>>(Wg, wgB, V_ * D_);

  embed_kernel<<<dim3((M_ * D_) / 256), 256, 0, stream>>>(inp, emb, x);

  dim3 gqkv(QKV_ / 128, M_ / 128);
  dim3 g512(D_ / 128, M_ / 128);
  dim3 gff(DFF_ / 128, M_ / 128);
  for (int l = 0; l < L_; l++) {
    ln_kernel<<<M_, 256, 0, stream>>>(x, ln1a + l * D_, ln1b + l * D_, hbuf);
    gemm128<0><<<gqkv, 256, 0, stream>>>(hbuf, wqkvB + (size_t)l * QKV_ * D_, bqkvB + l * QKV_, qkv, nullptr, M_, QKV_, D_);
    relbias_kernel<<<dim3((B_ * H_ * S_) / 256), 256, 0, stream>>>(qkv, rel + (size_t)l * H_ * (MAXSEQ_ + 1) * DK_, rbias);
    attn_kernel<<<dim3(S_ / QT, H_, B_), 256, 0, stream>>>(qkv, rbias, abuf);
    gemm128<3><<<g512, 256, 0, stream>>>(abuf, woB + (size_t)l * D_ * D_, bo + l * D_, x, x, M_, D_, D_);
    ln_kernel<<<M_, 256, 0, stream>>>(x, ln2a + l * D_, ln2b + l * D_, hbuf);
    gemm128<1><<<gff, 256, 0, stream>>>(hbuf, w1B + (size_t)l * DFF_ * D_, b1 + l * DFF_, ffn, nullptr, M_, DFF_, D_);
    gemm128<3><<<g512, 256, 0, stream>>>(ffn, w2B + (size_t)l * D_ * DFF_, b2 + l * D_, x, x, M_, D_, DFF_);
  }
  ln_kernel<<<M_, 256, 0, stream>>>(x, lnfa, lnfb, hbuf);
  dim3 gv(V_ / 128, M_ / 128);
  gemm128<0><<<gv, 256, 0, stream>>>(hbuf, wgB, bg, (float*)d_out, nullptr, M_, V_, D_);
  lsm_kernel<<<M_, 256, 0, stream>>>((float*)d_out);
}

// Round 5
// 1605.619 us; speedup vs baseline: 1.6289x; 1.3834x over previous
//
#include <hip/hip_runtime.h>
#include <math.h>

typedef __bf16 bf16;
typedef __bf16 bf16x8 __attribute__((ext_vector_type(8)));
typedef __bf16 bf16x4 __attribute__((ext_vector_type(4)));
typedef __bf16 bf16x2 __attribute__((ext_vector_type(2)));
typedef float f32x4 __attribute__((ext_vector_type(4)));

#define B_ 2
#define S_ 1024
#define D_ 512
#define H_ 8
#define L_ 6
#define DK_ 64
#define DFF_ 2048
#define V_ 32000
#define MAXSEQ_ 1024
#define M_ 2048           // B_*S_
#define QKV_ 1536         // 3*D_

#define GLDS16(g, l) __builtin_amdgcn_global_load_lds((const __attribute__((address_space(1))) void*)(g), (__attribute__((address_space(3))) void*)(l), 16, 0, 0)

// ---------------- block reduce helper (256 threads, 4 waves) ----------------
__device__ inline float blockReduceSum(float v, float* red) {
  for (int off = 32; off; off >>= 1) v += __shfl_xor(v, off, 64);
  int wid = threadIdx.x >> 6;
  __syncthreads();
  if ((threadIdx.x & 63) == 0) red[wid] = v;
  __syncthreads();
  return red[0] + red[1] + red[2] + red[3];
}

// ---------------- weight conversion: f32 -> bf16 ----------------
__global__ __launch_bounds__(256) void convw_kernel(const float* __restrict__ src,
                                                    bf16* __restrict__ dst, int n) {
  int i = (blockIdx.x * 256 + threadIdx.x) * 4;
  if (i < n) {
    float4 v = *(const float4*)(src + i);
    dst[i]     = (bf16)v.x;
    dst[i + 1] = (bf16)v.y;
    dst[i + 2] = (bf16)v.z;
    dst[i + 3] = (bf16)v.w;
  }
}

// merged QKV weights: dst[l][r][c], r in [0,1536): 0-511 Wq rows, 512-1023 Wk, 1024-1535 Wv
__global__ __launch_bounds__(256) void convqkv_kernel(const float* __restrict__ Wq,
                                                      const float* __restrict__ Wk,
                                                      const float* __restrict__ Wv,
                                                      bf16* __restrict__ dst) {
  int i = (blockIdx.x * 256 + threadIdx.x) * 4;   // over L_*QKV_*D_
  int l = i / (QKV_ * D_);
  int rem = i - l * (QKV_ * D_);
  int r = rem >> 9;
  int c = i & (D_ - 1);
  int which = r >> 9, rr = r & 511;
  const float* src = (which == 0 ? Wq : which == 1 ? Wk : Wv) + ((size_t)l * D_ + rr) * D_ + c;
  float4 v = *(const float4*)src;
  dst[i]     = (bf16)v.x;
  dst[i + 1] = (bf16)v.y;
  dst[i + 2] = (bf16)v.z;
  dst[i + 3] = (bf16)v.w;
}

__global__ __launch_bounds__(256) void convbqkv_kernel(const float* __restrict__ bq,
                                                       const float* __restrict__ bk,
                                                       const float* __restrict__ bv,
                                                       float* __restrict__ dst) {
  int i = blockIdx.x * 256 + threadIdx.x;
  if (i >= L_ * QKV_) return;
  int l = i / QKV_, r = i - l * QKV_;
  int which = r >> 9, rr = r & 511;
  const float* s = (which == 0 ? bq : which == 1 ? bk : bv);
  dst[i] = s[l * D_ + rr];
}

// ---------------- embedding + positional encoding ----------------
__global__ __launch_bounds__(256) void embed_kernel(const int* __restrict__ inp,
                                                    const float* __restrict__ emb,
                                                    float* __restrict__ x) {
  int i = blockIdx.x * 256 + threadIdx.x;
  int d = i & (D_ - 1);
  int s = (i >> 9) & (S_ - 1);
  int b = i >> 19;
  int tok = inp[b * S_ + s];
  int j2 = d & ~1;
  float div = expf(-(float)j2 * (9.210340371976184f / (float)D_));
  float ang = (float)s * div;
  float pe = (d & 1) ? cosf(ang) : sinf(ang);
  x[i] = emb[(size_t)tok * D_ + d] * 22.627416997969522f + pe;
}

// ---------------- layer norm ----------------
__global__ __launch_bounds__(256) void ln_kernel(const float* __restrict__ X,
                                                 const float* __restrict__ ga,
                                                 const float* __restrict__ gb,
                                                 bf16* __restrict__ out) {
  __shared__ float red[4];
  int row = blockIdx.x;
  const float* xr = X + (size_t)row * D_;
  int t = threadIdx.x;
  float x0 = xr[t], x1 = xr[t + 256];
  float mean = blockReduceSum(x0 + x1, red) * (1.0f / (float)D_);
  float d0 = x0 - mean, d1 = x1 - mean;
  float var = blockReduceSum(d0 * d0 + d1 * d1, red) * (1.0f / (float)(D_ - 1));
  float rs = 1.0f / (sqrtf(var) + 1e-6f);
  bf16* orow = out + (size_t)row * D_;
  orow[t]       = (bf16)(ga[t] * d0 * rs + gb[t]);
  orow[t + 256] = (bf16)(ga[t + 256] * d1 * rs + gb[t + 256]);
}

// ---------------- GEMM 128x128 tile: Y[m,n] = sum_k A[m,k]*W[n,k] + bias ----------------
// EPI: 0 = f32 out, 1 = relu -> bf16 out, 2 = bf16 out, 3 = f32 out + residual add
template <int EPI>
__global__ __launch_bounds__(256) void gemm128(const bf16* __restrict__ A,
                                               const bf16* __restrict__ W,
                                               const float* __restrict__ bias,
                                               void* __restrict__ Yv,
                                               const float* __restrict__ res,
                                               int M, int N, int K) {
  __shared__ __align__(16) bf16 As[128 * 32];
  __shared__ __align__(16) bf16 Bs[128 * 32];
  int t = threadIdx.x;
  int lane = t & 63, w = t >> 6;
  int n0 = blockIdx.x * 128, m0 = blockIdx.y * 128;
  int sr = lane >> 2, sc = (lane & 3) * 8;
  const bf16* ag0 = A + (size_t)(m0 + w * 16 + sr) * K + sc;
  const bf16* ag1 = A + (size_t)(m0 + (w + 4) * 16 + sr) * K + sc;
  const bf16* wg0 = W + (size_t)(n0 + w * 16 + sr) * K + sc;
  const bf16* wg1 = W + (size_t)(n0 + (w + 4) * 16 + sr) * K + sc;
  bf16* la0 = &As[w * 512];
  bf16* la1 = &As[(w + 4) * 512];
  bf16* lb0 = &Bs[w * 512];
  bf16* lb1 = &Bs[(w + 4) * 512];
  int wm = (w >> 1) * 64, wn = (w & 1) * 64;
  int fr = lane & 15, fk = (lane >> 4) * 8;
  f32x4 acc[4][4] = {};
  for (int kt = 0; kt < K; kt += 32) {
    GLDS16(ag0 + kt, la0);
    GLDS16(ag1 + kt, la1);
    GLDS16(wg0 + kt, lb0);
    GLDS16(wg1 + kt, lb1);
    __syncthreads();
    bf16x8 af[4], bfr[4];
    #pragma unroll
    for (int i = 0; i < 4; i++) af[i]  = *(const bf16x8*)&As[(wm + i * 16 + fr) * 32 + fk];
    #pragma unroll
    for (int i = 0; i < 4; i++) bfr[i] = *(const bf16x8*)&Bs[(wn + i * 16 + fr) * 32 + fk];
    #pragma unroll
    for (int mi = 0; mi < 4; mi++)
      #pragma unroll
      for (int ni = 0; ni < 4; ni++)
        acc[mi][ni] = __builtin_amdgcn_mfma_f32_16x16x32_bf16(af[mi], bfr[ni], acc[mi][ni], 0, 0, 0);
    __syncthreads();
  }
  int oc = lane & 15, orr = (lane >> 4) * 4;
  #pragma unroll
  for (int mi = 0; mi < 4; mi++)
    #pragma unroll
    for (int ni = 0; ni < 4; ni++)
      #pragma unroll
      for (int j = 0; j < 4; j++) {
        int row = m0 + wm + mi * 16 + orr + j;
        int col = n0 + wn + ni * 16 + oc;
        float val = acc[mi][ni][j] + bias[col];
        size_t idx = (size_t)row * N + col;
        if constexpr (EPI == 0)      ((float*)Yv)[idx] = val;
        else if constexpr (EPI == 1) ((bf16*)Yv)[idx] = (bf16)fmaxf(val, 0.0f);
        else if constexpr (EPI == 2) ((bf16*)Yv)[idx] = (bf16)val;
        else                         ((float*)Yv)[idx] = val + res[idx];
      }
}

// ---------------- relative-position bias: rb[b,h,k] = scale * dot(q[b,h,k,:], rel[h,k,:]) ----------------
__global__ __launch_bounds__(256) void relbias_kernel(const bf16* __restrict__ QKV,
                                                      const float* __restrict__ rel_l,
                                                      float* __restrict__ rb) {
  int i = blockIdx.x * 256 + threadIdx.x;   // over B*H*S = 16384
  int k = i & (S_ - 1);
  int h = (i >> 10) & (H_ - 1);
  int b = i >> 13;
  const bf16*  qp = QKV + ((size_t)(b * S_ + k)) * QKV_ + h * DK_;
  const float* rp = rel_l + ((size_t)h * (MAXSEQ_ + 1) + k) * DK_;
  float s = 0.f;
  #pragma unroll
  for (int j = 0; j < DK_; j++) s += (float)qp[j] * rp[j];
  rb[i] = s * 0.125f;
}

// ---------------- MFMA flash attention (swapped-operand, online softmax) ----------------
// QKV bf16 [M][1536]; per (b,h): Q at h*64, K at 512+h*64, V at 1024+h*64.
// Block: 128 threads (2 waves), 32 q-rows. S^T = mfma(K,Q); O^T = mfma(V^T, P^T).
__device__ inline int swzb(int b) { return b ^ (((b >> 7) & 7) << 4); }

__global__ __launch_bounds__(128) void attn_kernel(const bf16* __restrict__ QKV,
                                                   const float* __restrict__ rb,
                                                   bf16* __restrict__ Aout) {
  __shared__ __align__(16) bf16 vt[64 * 64];      // V^T [d][k], swizzled
  __shared__ __align__(16) bf16 pts[2][16 * 64];  // P [q][k] per wave, swizzled
  __shared__ float rb_s[64];
  int t = threadIdx.x;
  int lane = t & 63, w = t >> 6;
  int ql = lane & 15, g = lane >> 4;
  int qb = blockIdx.x * 32;
  int h = blockIdx.y, b = blockIdx.z;
  const bf16* Qb = QKV + (size_t)(b * S_) * QKV_ + h * DK_;
  const bf16* Kb = Qb + D_;
  const bf16* Vb = Qb + 2 * D_;
  const float* rbb = rb + (b * H_ + h) * S_;
  int qg = qb + w * 16 + ql;

  bf16x8 qf0 = *(const bf16x8*)(Qb + (size_t)qg * QKV_ + 8 * g);
  bf16x8 qf1 = *(const bf16x8*)(Qb + (size_t)qg * QKV_ + 32 + 8 * g);

  char* vtb = (char*)vt;
  char* ptb = (char*)&pts[w][0];

  float mrun = -1e30f, lrun = 0.f;
  f32x4 acc[4] = {};

  int nkt = qb / 64 + 1;
  for (int kt = 0; kt < nkt; kt++) {
    int kb = kt * 64;
    bool last = (kt == nkt - 1);
    __syncthreads();
    // stage V^T [d][k] (swizzled) + rb tile
    #pragma unroll
    for (int i = 0; i < 2; i++) {
      int slot = t + 128 * i;
      int kp = slot >> 3, dc = slot & 7;          // k-pair 0..31, d-chunk 0..7
      bf16x8 r0 = *(const bf16x8*)(Vb + (size_t)(kb + 2 * kp) * QKV_ + dc * 8);
      bf16x8 r1 = *(const bf16x8*)(Vb + (size_t)(kb + 2 * kp + 1) * QKV_ + dc * 8);
      #pragma unroll
      for (int u = 0; u < 8; u++) {
        int d = dc * 8 + u;
        *(bf16x2*)(vtb + swzb(d * 128 + kp * 4)) = (bf16x2){r0[u], r1[u]};
      }
    }
    if (t < 64) rb_s[t] = rbb[kb + t];
    __syncthreads();

    // scores: S^T[k][q] = sum_dk K[k][dk] Q[q][dk]
    f32x4 sc[4];
    #pragma unroll
    for (int ni = 0; ni < 4; ni++) {
      const bf16* krow = Kb + (size_t)(kb + 16 * ni + ql) * QKV_ + 8 * g;
      bf16x8 kf0 = *(const bf16x8*)(krow);
      bf16x8 kf1 = *(const bf16x8*)(krow + 32);
      f32x4 z = {};
      z = __builtin_amdgcn_mfma_f32_16x16x32_bf16(kf0, qf0, z, 0, 0, 0);
      z = __builtin_amdgcn_mfma_f32_16x16x32_bf16(kf1, qf1, z, 0, 0, 0);
      sc[ni] = z;
    }
    // scale + bias + mask, tile max
    float tmax = -1e30f;
    #pragma unroll
    for (int ni = 0; ni < 4; ni++)
      #pragma unroll
      for (int j = 0; j < 4; j++) {
        int kloc = 16 * ni + 4 * g + j;
        float s = fmaf(sc[ni][j], 0.125f, rb_s[kloc]);
        if (last && (kb + kloc > qg)) s = -1e9f;
        sc[ni][j] = s;
        tmax = fmaxf(tmax, s);
      }
    tmax = fmaxf(tmax, __shfl_xor(tmax, 16, 64));
    tmax = fmaxf(tmax, __shfl_xor(tmax, 32, 64));
    float mnew = fmaxf(mrun, tmax);
    float fac = __expf(mrun - mnew);
    #pragma unroll
    for (int nd = 0; nd < 4; nd++)
      #pragma unroll
      for (int j = 0; j < 4; j++) acc[nd][j] *= fac;
    float tsum = 0.f;
    #pragma unroll
    for (int ni = 0; ni < 4; ni++)
      #pragma unroll
      for (int j = 0; j < 4; j++) {
        float p = __expf(sc[ni][j] - mnew);
        sc[ni][j] = p;
        tsum += p;
      }
    tsum += __shfl_xor(tsum, 16, 64);
    tsum += __shfl_xor(tsum, 32, 64);
    lrun = lrun * fac + tsum;
    mrun = mnew;

    // P -> LDS [q][k] bf16, swizzled (wave-private)
    #pragma unroll
    for (int ni = 0; ni < 4; ni++) {
      int byte0 = ql * 128 + 32 * ni + 8 * g;
      *(bf16x2*)(ptb + swzb(byte0))     = (bf16x2){(bf16)sc[ni][0], (bf16)sc[ni][1]};
      *(bf16x2*)(ptb + swzb(byte0 + 4)) = (bf16x2){(bf16)sc[ni][2], (bf16)sc[ni][3]};
    }
    // PV: O^T[d][q] += sum_k V^T[d][k] P^T[k][q]
    bf16x8 pf0 = *(const bf16x8*)(ptb + swzb(ql * 128 + 16 * g));
    bf16x8 pf1 = *(const bf16x8*)(ptb + swzb(ql * 128 + 64 + 16 * g));
    #pragma unroll
    for (int nd = 0; nd < 4; nd++) {
      bf16x8 vf0 = *(const bf16x8*)(vtb + swzb((16 * nd + ql) * 128 + 16 * g));
      bf16x8 vf1 = *(const bf16x8*)(vtb + swzb((16 * nd + ql) * 128 + 64 + 16 * g));
      acc[nd] = __builtin_amdgcn_mfma_f32_16x16x32_bf16(vf0, pf0, acc[nd], 0, 0, 0);
      acc[nd] = __builtin_amdgcn_mfma_f32_16x16x32_bf16(vf1, pf1, acc[nd], 0, 0, 0);
    }
  }

  float inv = 1.0f / lrun;
  bf16* orow = Aout + (size_t)(b * S_ + qg) * D_ + h * DK_;
  #pragma unroll
  for (int nd = 0; nd < 4; nd++) {
    bf16x4 ov;
    #pragma unroll
    for (int j = 0; j < 4; j++) ov[j] = (bf16)(acc[nd][j] * inv);
    *(bf16x4*)(orow + 16 * nd + 4 * g) = ov;
  }
}

// ---------------- in-place log-softmax over V_ per row (float4) ----------------
__global__ __launch_bounds__(256) void lsm_kernel(float* __restrict__ X) {
  __shared__ float redm[4], reds[4], sh[1];
  int row = blockIdx.x;
  float4* xr = (float4*)(X + (size_t)row * V_);
  int t = threadIdx.x;
  float m = -1e30f, s = 0.f;
  for (int i = t; i < V_ / 4; i += 256) {
    float4 v = xr[i];
    float m4 = fmaxf(fmaxf(v.x, v.y), fmaxf(v.z, v.w));
    if (m4 > m) { s *= __expf(m - m4); m = m4; }
    s += __expf(v.x - m) + __expf(v.y - m) + __expf(v.z - m) + __expf(v.w - m);
  }
  for (int off = 32; off; off >>= 1) {
    float m2 = __shfl_xor(m, off, 64);
    float s2 = __shfl_xor(s, off, 64);
    float mn = fmaxf(m, m2);
    s = s * __expf(m - mn) + s2 * __expf(m2 - mn);
    m = mn;
  }
  int wid = t >> 6;
  if ((t & 63) == 0) { redm[wid] = m; reds[wid] = s; }
  __syncthreads();
  if (t == 0) {
    float M2 = redm[0], SS = reds[0];
    for (int i2 = 1; i2 < 4; i2++) {
      float mn = fmaxf(M2, redm[i2]);
      SS = SS * __expf(M2 - mn) + reds[i2] * __expf(redm[i2] - mn);
      M2 = mn;
    }
    sh[0] = M2 + logf(SS);
  }
  __syncthreads();
  float lz = sh[0];
  for (int i = t; i < V_ / 4; i += 256) {
    float4 v = xr[i];
    v.x -= lz; v.y -= lz; v.z -= lz; v.w -= lz;
    xr[i] = v;
  }
}

// ---------------- launch ----------------
extern "C" void kernel_launch(void* const* d_in, const int* in_sizes, int n_in,
                              void* d_out, int out_size, void* d_ws, size_t ws_size,
                              hipStream_t stream) {
  const int*   inp  = (const int*)d_in[0];
  const float* emb  = (const float*)d_in[2];
  const float* Wq   = (const float*)d_in[3];
  const float* bq   = (const float*)d_in[4];
  const float* Wk   = (const float*)d_in[5];
  const float* bk   = (const float*)d_in[6];
  const float* Wv   = (const float*)d_in[7];
  const float* bv   = (const float*)d_in[8];
  const float* Wo   = (const float*)d_in[9];
  const float* bo   = (const float*)d_in[10];
  const float* rel  = (const float*)d_in[11];
  const float* ln1a = (const float*)d_in[12];
  const float* ln1b = (const float*)d_in[13];
  const float* ln2a = (const float*)d_in[14];
  const float* ln2b = (const float*)d_in[15];
  const float* W1   = (const float*)d_in[16];
  const float* b1   = (const float*)d_in[17];
  const float* W2   = (const float*)d_in[18];
  const float* b2   = (const float*)d_in[19];
  const float* lnfa = (const float*)d_in[20];
  const float* lnfb = (const float*)d_in[21];
  const float* Wg   = (const float*)d_in[22];
  const float* bg   = (const float*)d_in[23];

  char* wp = (char*)d_ws;
  auto alloc = [&](size_t bytes) { void* p = wp; wp += (bytes + 255) & ~255ULL; return p; };
  float* x     = (float*)alloc((size_t)M_ * D_ * 4);
  bf16*  hbuf  = (bf16*) alloc((size_t)M_ * D_ * 2);
  bf16*  qkv   = (bf16*) alloc((size_t)M_ * QKV_ * 2);
  bf16*  abuf  = (bf16*) alloc((size_t)M_ * D_ * 2);
  bf16*  ffn   = (bf16*) alloc((size_t)M_ * DFF_ * 2);
  float* rbias = (float*)alloc((size_t)B_ * H_ * S_ * 4);
  bf16*  wqkvB = (bf16*) alloc((size_t)L_ * QKV_ * D_ * 2);
  float* bqkvB = (float*)alloc((size_t)L_ * QKV_ * 4);
  bf16*  woB   = (bf16*) alloc((size_t)L_ * D_ * D_ * 2);
  bf16*  w1B   = (bf16*) alloc((size_t)L_ * DFF_ * D_ * 2);
  bf16*  w2B   = (bf16*) alloc((size_t)L_ * D_ * DFF_ * 2);
  bf16*  wgB   = (bf16*) alloc((size_t)V_ * D_ * 2);

  convqkv_kernel<<<dim3(L_ * QKV_ * D_ / 1024), 256, 0, stream>>>(Wq, Wk, Wv, wqkvB);
  convbqkv_kernel<<<dim3((L_ * QKV_ + 255) / 256), 256, 0, stream>>>(bq, bk, bv, bqkvB);
  convw_kernel<<<dim3(L_ * D_ * D_ / 1024), 256, 0, stream>>>(Wo, woB, L_ * D_ * D_);
  convw_kernel<<<dim3(L_ * DFF_ * D_ / 1024), 256, 0, stream>>>(W1, w1B, L_ * DFF_ * D_);
  convw_kernel<<<dim3(L_ * D_ * DFF_ / 1024), 256, 0, stream>>>(W2, w2B, L_ * D_ * DFF_);
  convw_kernel<<<dim3(V_ * D_ / 1024), 256, 0, stream>>>(Wg, wgB, V_ * D_);

  embed_kernel<<<dim3((M_ * D_) / 256), 256, 0, stream>>>(inp, emb, x);

  dim3 gqkv(QKV_ / 128, M_ / 128);
  dim3 g512(D_ / 128, M_ / 128);
  dim3 gff(DFF_ / 128, M_ / 128);
  for (int l = 0; l < L_; l++) {
    ln_kernel<<<M_, 256, 0, stream>>>(x, ln1a + l * D_, ln1b + l * D_, hbuf);
    gemm128<2><<<gqkv, 256, 0, stream>>>(hbuf, wqkvB + (size_t)l * QKV_ * D_, bqkvB + l * QKV_, qkv, nullptr, M_, QKV_, D_);
    relbias_kernel<<<dim3((B_ * H_ * S_) / 256), 256, 0, stream>>>(qkv, rel + (size_t)l * H_ * (MAXSEQ_ + 1) * DK_, rbias);
    attn_kernel<<<dim3(S_ / 32, H_, B_), 128, 0, stream>>>(qkv, rbias, abuf);
    gemm128<3><<<g512, 256, 0, stream>>>(abuf, woB + (size_t)l * D_ * D_, bo + l * D_, x, x, M_, D_, D_);
    ln_kernel<<<M_, 256, 0, stream>>>(x, ln2a + l * D_, ln2b + l * D_, hbuf);
    gemm128<1><<<gff, 256, 0, stream>>>(hbuf, w1B + (size_t)l * DFF_ * D_, b1 + l * DFF_, ffn, nullptr, M_, DFF_, D_);
    gemm128<3><<<g512, 256, 0, stream>>>(ffn, w2B + (size_t)l * D_ * DFF_, b2 + l * D_, x, x, M_, D_, DFF_);
  }
  ln_kernel<<<M_, 256, 0, stream>>>(x, lnfa, lnfb, hbuf);
  dim3 gv(V_ / 128, M_ / 128);
  gemm128<0><<<gv, 256, 0, stream>>>(hbuf, wgB, bg, (float*)d_out, nullptr, M_, V_, D_);
  lsm_kernel<<<M_, 256, 0, stream>>>((float*)d_out);
}

// Round 7
// 1375.470 us; speedup vs baseline: 1.9014x; 1.1673x over previous
//
#include <hip/hip_runtime.h>
#include <math.h>

typedef __bf16 bf16;
typedef __bf16 bf16x8 __attribute__((ext_vector_type(8)));
typedef __bf16 bf16x4 __attribute__((ext_vector_type(4)));
typedef __bf16 bf16x2 __attribute__((ext_vector_type(2)));
typedef float f32x4 __attribute__((ext_vector_type(4)));

#define B_ 2
#define S_ 1024
#define D_ 512
#define H_ 8
#define L_ 6
#define DK_ 64
#define DFF_ 2048
#define V_ 32000
#define MAXSEQ_ 1024
#define M_ 2048           // B_*S_
#define QKV_ 1536         // 3*D_

#define GLDS16(g, l) __builtin_amdgcn_global_load_lds((const __attribute__((address_space(1))) void*)(g), (__attribute__((address_space(3))) void*)(l), 16, 0, 0)

// ---------------- block reduce helper (256 threads, 4 waves) ----------------
__device__ inline float blockReduceSum(float v, float* red) {
  for (int off = 32; off; off >>= 1) v += __shfl_xor(v, off, 64);
  int wid = threadIdx.x >> 6;
  __syncthreads();
  if ((threadIdx.x & 63) == 0) red[wid] = v;
  __syncthreads();
  return red[0] + red[1] + red[2] + red[3];
}

// ---------------- weight conversion: f32 -> bf16 ----------------
__global__ __launch_bounds__(256) void convw_kernel(const float* __restrict__ src,
                                                    bf16* __restrict__ dst, int n) {
  int i = (blockIdx.x * 256 + threadIdx.x) * 4;
  if (i < n) {
    float4 v = *(const float4*)(src + i);
    dst[i]     = (bf16)v.x;
    dst[i + 1] = (bf16)v.y;
    dst[i + 2] = (bf16)v.z;
    dst[i + 3] = (bf16)v.w;
  }
}

// merged QKV weights: dst[l][r][c], r in [0,1536): 0-511 Wq rows, 512-1023 Wk, 1024-1535 Wv
__global__ __launch_bounds__(256) void convqkv_kernel(const float* __restrict__ Wq,
                                                      const float* __restrict__ Wk,
                                                      const float* __restrict__ Wv,
                                                      bf16* __restrict__ dst) {
  int i = (blockIdx.x * 256 + threadIdx.x) * 4;   // over L_*QKV_*D_
  int l = i / (QKV_ * D_);
  int rem = i - l * (QKV_ * D_);
  int r = rem >> 9;
  int c = i & (D_ - 1);
  int which = r >> 9, rr = r & 511;
  const float* src = (which == 0 ? Wq : which == 1 ? Wk : Wv) + ((size_t)l * D_ + rr) * D_ + c;
  float4 v = *(const float4*)src;
  dst[i]     = (bf16)v.x;
  dst[i + 1] = (bf16)v.y;
  dst[i + 2] = (bf16)v.z;
  dst[i + 3] = (bf16)v.w;
}

__global__ __launch_bounds__(256) void convbqkv_kernel(const float* __restrict__ bq,
                                                       const float* __restrict__ bk,
                                                       const float* __restrict__ bv,
                                                       float* __restrict__ dst) {
  int i = blockIdx.x * 256 + threadIdx.x;
  if (i >= L_ * QKV_) return;
  int l = i / QKV_, r = i - l * QKV_;
  int which = r >> 9, rr = r & 511;
  const float* s = (which == 0 ? bq : which == 1 ? bk : bv);
  dst[i] = s[l * D_ + rr];
}

// ---------------- embedding + positional encoding ----------------
__global__ __launch_bounds__(256) void embed_kernel(const int* __restrict__ inp,
                                                    const float* __restrict__ emb,
                                                    float* __restrict__ x) {
  int i = blockIdx.x * 256 + threadIdx.x;
  int d = i & (D_ - 1);
  int s = (i >> 9) & (S_ - 1);
  int b = i >> 19;
  int tok = inp[b * S_ + s];
  int j2 = d & ~1;
  float div = expf(-(float)j2 * (9.210340371976184f / (float)D_));
  float ang = (float)s * div;
  float pe = (d & 1) ? cosf(ang) : sinf(ang);
  x[i] = emb[(size_t)tok * D_ + d] * 22.627416997969522f + pe;
}

// ---------------- layer norm ----------------
__global__ __launch_bounds__(256) void ln_kernel(const float* __restrict__ X,
                                                 const float* __restrict__ ga,
                                                 const float* __restrict__ gb,
                                                 bf16* __restrict__ out) {
  __shared__ float red[4];
  int row = blockIdx.x;
  const float* xr = X + (size_t)row * D_;
  int t = threadIdx.x;
  float x0 = xr[t], x1 = xr[t + 256];
  float mean = blockReduceSum(x0 + x1, red) * (1.0f / (float)D_);
  float d0 = x0 - mean, d1 = x1 - mean;
  float var = blockReduceSum(d0 * d0 + d1 * d1, red) * (1.0f / (float)(D_ - 1));
  float rs = 1.0f / (sqrtf(var) + 1e-6f);
  bf16* orow = out + (size_t)row * D_;
  orow[t]       = (bf16)(ga[t] * d0 * rs + gb[t]);
  orow[t + 256] = (bf16)(ga[t + 256] * d1 * rs + gb[t + 256]);
}

// ---------------- generic GEMM: Y[m,n] = sum_k A[m,k]*W[n,k] (+bias) ----------------
// Single-barrier double-buffered K-loop; quad-XOR swizzled LDS (pre-swizzled global src).
// EPI: 1 = relu -> bf16, 2 = bf16 out, 4 = atomicAdd into f32 (bias only when blockIdx.z==0)
template <int BM, int BN, int EPI, int SK>
__global__ __launch_bounds__(256) void gemm_t(const bf16* __restrict__ A,
                                              const bf16* __restrict__ W,
                                              const float* __restrict__ bias,
                                              void* __restrict__ Yv,
                                              int M, int N, int K) {
  constexpr int SMH = (BM + BN) * 32;
  constexpr int NL  = (BM + BN) / 64;
  constexpr int AF  = BM / 32, BF = BN / 32;
  __shared__ __align__(16) bf16 sm[2 * SMH];
  int t = threadIdx.x, lane = t & 63, w = t >> 6;
  int n0 = blockIdx.x * BN, m0 = blockIdx.y * BM;
  int koff = blockIdx.z * (K / SK);
  int NT = (K / SK) / 32;
  int wm = (w >> 1) * (BM / 2), wn = (w & 1) * (BN / 2);
  int fr = lane & 15, g = lane >> 4;
  int sr = lane >> 2;
  int scq = ((lane & 3) ^ ((lane >> 2) & 3)) << 3;   // pre-swizzled source quad

  f32x4 acc[AF][BF] = {};

  auto stage = [&](int kt, int buf) {
    bf16* base = sm + buf * SMH;
    #pragma unroll
    for (int i = 0; i < NL; i++) {
      int chunk = i * 4 + w;
      int kk = koff + kt * 32 + scq;
      const bf16* gp;
      if (i * 64 < BM) gp = A + (size_t)(m0 + chunk * 16 + sr) * K + kk;
      else             gp = W + (size_t)(n0 + chunk * 16 - BM + sr) * K + kk;
      GLDS16(gp, base + chunk * 512);
    }
  };

  stage(0, 0);
  int cur = 0;
  for (int kt = 0; kt < NT; kt++) {
    __syncthreads();                       // drains stage(kt); frees other buffer
    if (kt + 1 < NT) stage(kt + 1, cur ^ 1);  // in flight under this tile's compute
    const bf16* As = sm + cur * SMH;
    const bf16* Bs = As + BM * 32;
    bf16x8 af[AF], bfv[BF];
    #pragma unroll
    for (int i = 0; i < AF; i++) {
      int row = wm + i * 16 + fr;
      af[i] = *(const bf16x8*)((const char*)As + row * 64 + ((g ^ (row & 3)) << 4));
    }
    #pragma unroll
    for (int i = 0; i < BF; i++) {
      int row = wn + i * 16 + fr;
      bfv[i] = *(const bf16x8*)((const char*)Bs + row * 64 + ((g ^ (row & 3)) << 4));
    }
    #pragma unroll
    for (int mi = 0; mi < AF; mi++)
      #pragma unroll
      for (int ni = 0; ni < BF; ni++)
        acc[mi][ni] = __builtin_amdgcn_mfma_f32_16x16x32_bf16(af[mi], bfv[ni], acc[mi][ni], 0, 0, 0);
    cur ^= 1;
  }

  int oc = lane & 15, orr = g * 4;
  bool addb = (SK == 1) || (blockIdx.z == 0);
  #pragma unroll
  for (int mi = 0; mi < AF; mi++)
    #pragma unroll
    for (int ni = 0; ni < BF; ni++)
      #pragma unroll
      for (int j = 0; j < 4; j++) {
        int row = m0 + wm + mi * 16 + orr + j;
        int col = n0 + wn + ni * 16 + oc;
        float val = acc[mi][ni][j];
        size_t idx = (size_t)row * N + col;
        if constexpr (EPI == 1)      ((bf16*)Yv)[idx] = (bf16)fmaxf(val + bias[col], 0.0f);
        else if constexpr (EPI == 2) ((bf16*)Yv)[idx] = (bf16)(val + bias[col]);
        else {
          if (addb) val += bias[col];
          unsafeAtomicAdd((float*)Yv + idx, val);
        }
      }
}

// ---------------- relative-position bias: rb[b,h,k] = scale * dot(q[b,h,k,:], rel[h,k,:]) ----------------
__global__ __launch_bounds__(256) void relbias_kernel(const bf16* __restrict__ QKV,
                                                      const float* __restrict__ rel_l,
                                                      float* __restrict__ rb) {
  int i = blockIdx.x * 256 + threadIdx.x;   // over B*H*S = 16384
  int k = i & (S_ - 1);
  int h = (i >> 10) & (H_ - 1);
  int b = i >> 13;
  const bf16*  qp = QKV + ((size_t)(b * S_ + k)) * QKV_ + h * DK_;
  const float* rp = rel_l + ((size_t)h * (MAXSEQ_ + 1) + k) * DK_;
  float s = 0.f;
  #pragma unroll
  for (int j = 0; j < DK_; j++) s += (float)qp[j] * rp[j];
  rb[i] = s * 0.125f;
}

// ---------------- MFMA flash attention (swapped-operand, online softmax) ----------------
__device__ inline int swzb(int b) { return b ^ (((b >> 7) & 7) << 4); }

__global__ __launch_bounds__(128) void attn_kernel(const bf16* __restrict__ QKV,
                                                   const float* __restrict__ rb,
                                                   bf16* __restrict__ Aout) {
  __shared__ __align__(16) bf16 vt[64 * 64];      // V^T [d][k], swizzled
  __shared__ __align__(16) bf16 pts[2][16 * 64];  // P [q][k] per wave, swizzled
  __shared__ float rb_s[64];
  int t = threadIdx.x;
  int lane = t & 63, w = t >> 6;
  int ql = lane & 15, g = lane >> 4;
  int qb = blockIdx.x * 32;
  int h = blockIdx.y, b = blockIdx.z;
  const bf16* Qb = QKV + (size_t)(b * S_) * QKV_ + h * DK_;
  const bf16* Kb = Qb + D_;
  const bf16* Vb = Qb + 2 * D_;
  const float* rbb = rb + (b * H_ + h) * S_;
  int qg = qb + w * 16 + ql;

  bf16x8 qf0 = *(const bf16x8*)(Qb + (size_t)qg * QKV_ + 8 * g);
  bf16x8 qf1 = *(const bf16x8*)(Qb + (size_t)qg * QKV_ + 32 + 8 * g);

  char* vtb = (char*)vt;
  char* ptb = (char*)&pts[w][0];

  float mrun = -1e30f, lrun = 0.f;
  f32x4 acc[4] = {};

  int nkt = qb / 64 + 1;
  for (int kt = 0; kt < nkt; kt++) {
    int kb = kt * 64;
    bool last = (kt == nkt - 1);
    __syncthreads();
    #pragma unroll
    for (int i = 0; i < 2; i++) {
      int slot = t + 128 * i;
      int kp = slot >> 3, dc = slot & 7;
      bf16x8 r0 = *(const bf16x8*)(Vb + (size_t)(kb + 2 * kp) * QKV_ + dc * 8);
      bf16x8 r1 = *(const bf16x8*)(Vb + (size_t)(kb + 2 * kp + 1) * QKV_ + dc * 8);
      #pragma unroll
      for (int u = 0; u < 8; u++) {
        int d = dc * 8 + u;
        *(bf16x2*)(vtb + swzb(d * 128 + kp * 4)) = (bf16x2){r0[u], r1[u]};
      }
    }
    if (t < 64) rb_s[t] = rbb[kb + t];
    __syncthreads();

    f32x4 sc[4];
    #pragma unroll
    for (int ni = 0; ni < 4; ni++) {
      const bf16* krow = Kb + (size_t)(kb + 16 * ni + ql) * QKV_ + 8 * g;
      bf16x8 kf0 = *(const bf16x8*)(krow);
      bf16x8 kf1 = *(const bf16x8*)(krow + 32);
      f32x4 z = {};
      z = __builtin_amdgcn_mfma_f32_16x16x32_bf16(kf0, qf0, z, 0, 0, 0);
      z = __builtin_amdgcn_mfma_f32_16x16x32_bf16(kf1, qf1, z, 0, 0, 0);
      sc[ni] = z;
    }
    float tmax = -1e30f;
    #pragma unroll
    for (int ni = 0; ni < 4; ni++)
      #pragma unroll
      for (int j = 0; j < 4; j++) {
        int kloc = 16 * ni + 4 * g + j;
        float s = fmaf(sc[ni][j], 0.125f, rb_s[kloc]);
        if (last && (kb + kloc > qg)) s = -1e9f;
        sc[ni][j] = s;
        tmax = fmaxf(tmax, s);
      }
    tmax = fmaxf(tmax, __shfl_xor(tmax, 16, 64));
    tmax = fmaxf(tmax, __shfl_xor(tmax, 32, 64));
    float mnew = fmaxf(mrun, tmax);
    float fac = __expf(mrun - mnew);
    #pragma unroll
    for (int nd = 0; nd < 4; nd++)
      #pragma unroll
      for (int j = 0; j < 4; j++) acc[nd][j] *= fac;
    float tsum = 0.f;
    #pragma unroll
    for (int ni = 0; ni < 4; ni++)
      #pragma unroll
      for (int j = 0; j < 4; j++) {
        float p = __expf(sc[ni][j] - mnew);
        sc[ni][j] = p;
        tsum += p;
      }
    tsum += __shfl_xor(tsum, 16, 64);
    tsum += __shfl_xor(tsum, 32, 64);
    lrun = lrun * fac + tsum;
    mrun = mnew;

    #pragma unroll
    for (int ni = 0; ni < 4; ni++) {
      int byte0 = ql * 128 + 32 * ni + 8 * g;
      *(bf16x2*)(ptb + swzb(byte0))     = (bf16x2){(bf16)sc[ni][0], (bf16)sc[ni][1]};
      *(bf16x2*)(ptb + swzb(byte0 + 4)) = (bf16x2){(bf16)sc[ni][2], (bf16)sc[ni][3]};
    }
    bf16x8 pf0 = *(const bf16x8*)(ptb + swzb(ql * 128 + 16 * g));
    bf16x8 pf1 = *(const bf16x8*)(ptb + swzb(ql * 128 + 64 + 16 * g));
    #pragma unroll
    for (int nd = 0; nd < 4; nd++) {
      bf16x8 vf0 = *(const bf16x8*)(vtb + swzb((16 * nd + ql) * 128 + 16 * g));
      bf16x8 vf1 = *(const bf16x8*)(vtb + swzb((16 * nd + ql) * 128 + 64 + 16 * g));
      acc[nd] = __builtin_amdgcn_mfma_f32_16x16x32_bf16(vf0, pf0, acc[nd], 0, 0, 0);
      acc[nd] = __builtin_amdgcn_mfma_f32_16x16x32_bf16(vf1, pf1, acc[nd], 0, 0, 0);
    }
  }

  float inv = 1.0f / lrun;
  bf16* orow = Aout + (size_t)(b * S_ + qg) * D_ + h * DK_;
  #pragma unroll
  for (int nd = 0; nd < 4; nd++) {
    bf16x4 ov;
    #pragma unroll
    for (int j = 0; j < 4; j++) ov[j] = (bf16)(acc[nd][j] * inv);
    *(bf16x4*)(orow + 16 * nd + 4 * g) = ov;
  }
}

// ---------------- log-softmax: bf16 logits -> f32 out ----------------
__global__ __launch_bounds__(256) void lsm_kernel(const bf16* __restrict__ Lg,
                                                  float* __restrict__ out) {
  __shared__ float redm[4], reds[4], sh[1];
  int row = blockIdx.x;
  const bf16x8* lr = (const bf16x8*)(Lg + (size_t)row * V_);
  int t = threadIdx.x;
  float m = -1e30f, s = 0.f;
  for (int i = t; i < V_ / 8; i += 256) {
    bf16x8 v = lr[i];
    float f[8];
    #pragma unroll
    for (int e = 0; e < 8; e++) f[e] = (float)v[e];
    float m8 = f[0];
    #pragma unroll
    for (int e = 1; e < 8; e++) m8 = fmaxf(m8, f[e]);
    if (m8 > m) { s *= __expf(m - m8); m = m8; }
    #pragma unroll
    for (int e = 0; e < 8; e++) s += __expf(f[e] - m);
  }
  for (int off = 32; off; off >>= 1) {
    float m2 = __shfl_xor(m, off, 64);
    float s2 = __shfl_xor(s, off, 64);
    float mn = fmaxf(m, m2);
    s = s * __expf(m - mn) + s2 * __expf(m2 - mn);
    m = mn;
  }
  int wid = t >> 6;
  if ((t & 63) == 0) { redm[wid] = m; reds[wid] = s; }
  __syncthreads();
  if (t == 0) {
    float M2 = redm[0], SS = reds[0];
    for (int i2 = 1; i2 < 4; i2++) {
      float mn = fmaxf(M2, redm[i2]);
      SS = SS * __expf(M2 - mn) + reds[i2] * __expf(redm[i2] - mn);
      M2 = mn;
    }
    sh[0] = M2 + logf(SS);
  }
  __syncthreads();
  float lz = sh[0];
  float4* orow = (float4*)(out + (size_t)row * V_);
  for (int i = t; i < V_ / 8; i += 256) {
    bf16x8 v = lr[i];
    float4 a, b2;
    a.x = (float)v[0] - lz; a.y = (float)v[1] - lz; a.z = (float)v[2] - lz; a.w = (float)v[3] - lz;
    b2.x = (float)v[4] - lz; b2.y = (float)v[5] - lz; b2.z = (float)v[6] - lz; b2.w = (float)v[7] - lz;
    orow[i * 2]     = a;
    orow[i * 2 + 1] = b2;
  }
}

// ---------------- launch ----------------
extern "C" void kernel_launch(void* const* d_in, const int* in_sizes, int n_in,
                              void* d_out, int out_size, void* d_ws, size_t ws_size,
                              hipStream_t stream) {
  const int*   inp  = (const int*)d_in[0];
  const float* emb  = (const float*)d_in[2];
  const float* Wq   = (const float*)d_in[3];
  const float* bq   = (const float*)d_in[4];
  const float* Wk   = (const float*)d_in[5];
  const float* bk   = (const float*)d_in[6];
  const float* Wv   = (const float*)d_in[7];
  const float* bv   = (const float*)d_in[8];
  const float* Wo   = (const float*)d_in[9];
  const float* bo   = (const float*)d_in[10];
  const float* rel  = (const float*)d_in[11];
  const float* ln1a = (const float*)d_in[12];
  const float* ln1b = (const float*)d_in[13];
  const float* ln2a = (const float*)d_in[14];
  const float* ln2b = (const float*)d_in[15];
  const float* W1   = (const float*)d_in[16];
  const float* b1   = (const float*)d_in[17];
  const float* W2   = (const float*)d_in[18];
  const float* b2   = (const float*)d_in[19];
  const float* lnfa = (const float*)d_in[20];
  const float* lnfb = (const float*)d_in[21];
  const float* Wg   = (const float*)d_in[22];
  const float* bg   = (const float*)d_in[23];

  char* wp = (char*)d_ws;
  auto alloc = [&](size_t bytes) { void* p = wp; wp += (bytes + 255) & ~255ULL; return p; };
  float* x     = (float*)alloc((size_t)M_ * D_ * 4);
  bf16*  hbuf  = (bf16*) alloc((size_t)M_ * D_ * 2);
  bf16*  qkv   = (bf16*) alloc((size_t)M_ * QKV_ * 2);
  bf16*  abuf  = (bf16*) alloc((size_t)M_ * D_ * 2);
  bf16*  ffn   = (bf16*) alloc((size_t)M_ * DFF_ * 2);
  float* rbias = (float*)alloc((size_t)B_ * H_ * S_ * 4);
  bf16*  lgbuf = (bf16*) alloc((size_t)M_ * V_ * 2);
  bf16*  wqkvB = (bf16*) alloc((size_t)L_ * QKV_ * D_ * 2);
  float* bqkvB = (float*)alloc((size_t)L_ * QKV_ * 4);
  bf16*  woB   = (bf16*) alloc((size_t)L_ * D_ * D_ * 2);
  bf16*  w1B   = (bf16*) alloc((size_t)L_ * DFF_ * D_ * 2);
  bf16*  w2B   = (bf16*) alloc((size_t)L_ * D_ * DFF_ * 2);
  bf16*  wgB   = (bf16*) alloc((size_t)V_ * D_ * 2);

  convqkv_kernel<<<dim3(L_ * QKV_ * D_ / 1024), 256, 0, stream>>>(Wq, Wk, Wv, wqkvB);
  convbqkv_kernel<<<dim3((L_ * QKV_ + 255) / 256), 256, 0, stream>>>(bq, bk, bv, bqkvB);
  convw_kernel<<<dim3(L_ * D_ * D_ / 1024), 256, 0, stream>>>(Wo, woB, L_ * D_ * D_);
  convw_kernel<<<dim3(L_ * DFF_ * D_ / 1024), 256, 0, stream>>>(W1, w1B, L_ * DFF_ * D_);
  convw_kernel<<<dim3(L_ * D_ * DFF_ / 1024), 256, 0, stream>>>(W2, w2B, L_ * D_ * DFF_);
  convw_kernel<<<dim3(V_ * D_ / 1024), 256, 0, stream>>>(Wg, wgB, V_ * D_);

  embed_kernel<<<dim3((M_ * D_) / 256), 256, 0, stream>>>(inp, emb, x);

  for (int l = 0; l < L_; l++) {
    ln_kernel<<<M_, 256, 0, stream>>>(x, ln1a + l * D_, ln1b + l * D_, hbuf);
    gemm_t<64, 128, 2, 1><<<dim3(QKV_ / 128, M_ / 64), 256, 0, stream>>>(
        hbuf, wqkvB + (size_t)l * QKV_ * D_, bqkvB + l * QKV_, qkv, M_, QKV_, D_);
    relbias_kernel<<<dim3((B_ * H_ * S_) / 256), 256, 0, stream>>>(qkv, rel + (size_t)l * H_ * (MAXSEQ_ + 1) * DK_, rbias);
    attn_kernel<<<dim3(S_ / 32, H_, B_), 128, 0, stream>>>(qkv, rbias, abuf);
    gemm_t<64, 64, 4, 2><<<dim3(D_ / 64, M_ / 64, 2), 256, 0, stream>>>(
        abuf, woB + (size_t)l * D_ * D_, bo + l * D_, x, M_, D_, D_);
    ln_kernel<<<M_, 256, 0, stream>>>(x, ln2a + l * D_, ln2b + l * D_, hbuf);
    gemm_t<64, 128, 1, 1><<<dim3(DFF_ / 128, M_ / 64), 256, 0, stream>>>(
        hbuf, w1B + (size_t)l * DFF_ * D_, b1 + l * DFF_, ffn, M_, DFF_, D_);
    gemm_t<64, 64, 4, 4><<<dim3(D_ / 64, M_ / 64, 4), 256, 0, stream>>>(
        ffn, w2B + (size_t)l * D_ * DFF_, b2 + l * D_, x, M_, D_, DFF_);
  }
  ln_kernel<<<M_, 256, 0, stream>>>(x, lnfa, lnfb, hbuf);
  gemm_t<128, 128, 2, 1><<<dim3(V_ / 128, M_ / 128), 256, 0, stream>>>(
      hbuf, wgB, bg, lgbuf, M_, V_, D_);
  lsm_kernel<<<M_, 256, 0, stream>>>(lgbuf, (float*)d_out);
}